// Round 4
// baseline (2867.137 us; speedup 1.0000x reference)
//
#include <hip/hip_runtime.h>

#define NNODES 100000
#define NEDGES 3200000
#define NFEAT  512
#define NHID   256
#define NCLS   64
#define NLAYERS 8
#define SCAN_NB ((NNODES + 1023) / 1024)   // 98 blocks
#define SC_NPASS 4                          // scatter row-range passes (25000 rows each)

typedef short s8v __attribute__((ext_vector_type(8)));          // 8 bf16 (16B) MFMA frag
typedef unsigned short u8v __attribute__((ext_vector_type(8))); // 8 bf16 raw (16B)
typedef unsigned int u4v __attribute__((ext_vector_type(4)));   // 4 u32 (16B)
typedef float f4v __attribute__((ext_vector_type(4)));          // 4 f32 MFMA C/D frag
typedef float f2v __attribute__((ext_vector_type(2)));          // packed f32 pair

__device__ __forceinline__ float bf2f(unsigned short u) {
    union { unsigned int i; float f; } v; v.i = ((unsigned int)u) << 16; return v.f;
}
__device__ __forceinline__ unsigned short f2bf(float f) {
    union { float f; unsigned int u; } v; v.f = f;
    unsigned int u = v.u;
    u += 0x7FFFu + ((u >> 16) & 1u);   // RNE
    return (unsigned short)(u >> 16);
}
__device__ __forceinline__ float ldf(const void* p, size_t i, int f32) {
    return f32 ? ((const float*)p)[i] : bf2f(((const unsigned short*)p)[i]);
}
// combined edge record: low 32 = col, high 32 = f32 weight bits
__device__ __forceinline__ int em_col(long long m) { return (int)(unsigned int)m; }
__device__ __forceinline__ float em_w(long long m) {
    union { int i; float f; } u; u.i = (int)((unsigned long long)m >> 32); return u.f;
}
// expand packed 2x bf16 word -> f32 pair {lo, hi}
__device__ __forceinline__ f2v ex2(unsigned int v) {
    union { unsigned int u; float f; } lo, hi;
    lo.u = v << 16; hi.u = v & 0xFFFF0000u;
    return (f2v){lo.f, hi.f};
}
// LDS XOR swizzle: spread 512B-stride rows across banks (bits 4-6)
#define SW(off, row) ((off) ^ (((row) & 7) << 4))

// ---------------- dtype probe ----------------
__global__ void probe_kernel(const unsigned short* __restrict__ ew, int* __restrict__ flag) {
    int i = threadIdx.x;                       // 64 threads
    unsigned short v = ew[2 * i];
    bool bad = (v & 0x8000u) || (v > 0x3D80u);
    unsigned long long m = __ballot(bad);
    if (i == 0) *flag = (m != 0ull) ? 1 : 0;   // 1 => float32 storage
}

// ---------------- CSR build ----------------
__global__ void hist_kernel(const int* __restrict__ row, int* __restrict__ counts) {
    int e = blockIdx.x * 256 + threadIdx.x;
    if (e < NEDGES) atomicAdd(&counts[__builtin_nontemporal_load(row + e)], 1);
}

__global__ void scan_local(const int* __restrict__ counts, int* __restrict__ row_ptr,
                           int* __restrict__ bsum) {
    __shared__ int lds[1024];
    const int tid = threadIdx.x;
    const int i = blockIdx.x * 1024 + tid;
    int v = (i < NNODES) ? counts[i] : 0;
    lds[tid] = v;
    __syncthreads();
    for (int off = 1; off < 1024; off <<= 1) {
        int t = (tid >= off) ? lds[tid - off] : 0;
        __syncthreads();
        lds[tid] += t;
        __syncthreads();
    }
    if (i < NNODES) row_ptr[i] = lds[tid] - v;      // block-local exclusive
    if (tid == 1023) bsum[blockIdx.x] = lds[1023];  // block total
}

__global__ void scan_bsum(int* __restrict__ bsum) {
    if (threadIdx.x == 0) {
        int acc = 0;
        for (int i = 0; i < SCAN_NB; ++i) { int v = bsum[i]; bsum[i] = acc; acc += v; }
        bsum[SCAN_NB] = acc;
    }
}

__global__ void scan_add(int* __restrict__ row_ptr, int* __restrict__ cursor,
                         const int* __restrict__ bsum) {
    const int i = blockIdx.x * 1024 + threadIdx.x;
    if (i < NNODES) {
        int v = row_ptr[i] + bsum[blockIdx.x];
        row_ptr[i] = v;
        cursor[i]  = v;
    }
    if (i == NNODES) row_ptr[NNODES] = bsum[SCAN_NB];
}

// row-range-binned scatter: pass handles rows [lo,hi); active em window = 6.4 MB
// (L2-resident) so each 64B line fills completely before eviction. Streaming
// inputs use nt loads so they don't evict partially-filled em lines.
__global__ __launch_bounds__(256) void scatter_pass(
    const int* __restrict__ row, const int* __restrict__ col,
    const void* __restrict__ w, int* __restrict__ cursor,
    long long* __restrict__ em, const int* __restrict__ flagp,
    int lo, int hi)
{
    const int f32 = *flagp;
    int e = blockIdx.x * 256 + threadIdx.x;
    if (e >= NEDGES) return;
    int r = __builtin_nontemporal_load(row + e);
    if (r < lo || r >= hi) return;
    int c = __builtin_nontemporal_load(col + e);
    float wv = f32 ? __builtin_nontemporal_load((const float*)w + e)
                   : bf2f(__builtin_nontemporal_load((const unsigned short*)w + e));
    union { float f; unsigned int u; } uw; uw.f = wv;
    long long rec = ((long long)uw.u << 32) | (unsigned int)c;
    int pos = atomicAdd(&cursor[r], 1);
    em[pos] = rec;
}

// ---------------- B-matrix repack into MFMA fragment order ----------------
template<int K, int N>
__global__ void pack_b(const void* __restrict__ src, unsigned short* __restrict__ dst,
                       const int* __restrict__ flagp) {
    const int f32 = *flagp;
    const int NT = N / 16;
    const int total = (K / 32) * NT * 64;
    int tid = blockIdx.x * 256 + threadIdx.x;
    if (tid >= total) return;
    int lane = tid & 63, rest = tid >> 6;
    int nt = rest % NT, ks = rest / NT;
    int n  = nt * 16 + (lane & 15);
    int kb = ks * 32 + (lane >> 4) * 8;
    unsigned short tmp[8];
#pragma unroll
    for (int j = 0; j < 8; ++j) tmp[j] = f2bf(ldf(src, (size_t)(kb + j) * N + n, f32));
#pragma unroll
    for (int j = 0; j < 8; ++j) dst[(size_t)tid * 8 + j] = tmp[j];
}

// Wcomb_l = ((1-beta_l) I + beta_l W_l) @ W_sort  (256 x 64), packed B-frag layout, bf16.
__global__ void pack_wcomb(const void* __restrict__ Ws, const void* __restrict__ Wsort,
                           unsigned short* __restrict__ dst, const int* __restrict__ flagp) {
    const int f32 = *flagp;
    int tid = blockIdx.x * 256 + threadIdx.x;
    if (tid >= 16384) return;
    int lane = tid & 63;
    int rest = tid >> 6;
    int nt = rest & 3;
    int ks = (rest >> 2) & 7;
    int l  = rest >> 5;
    int n  = nt * 16 + (lane & 15);
    int kb = ks * 32 + (lane >> 4) * 8;
    float beta = 0.5f / (float)(l + 1);
    float ombeta = 1.0f - beta;
    const size_t wl = (size_t)l * NHID * NHID;
    unsigned short tmp[8];
#pragma unroll
    for (int j = 0; j < 8; ++j) {
        int k = kb + j;
        float s = 0.0f;
        for (int q = 0; q < NHID; ++q)
            s = fmaf(ldf(Ws, wl + (size_t)k * NHID + q, f32),
                     ldf(Wsort, (size_t)q * NCLS + n, f32), s);
        tmp[j] = f2bf(ombeta * ldf(Wsort, (size_t)k * NCLS + n, f32) + beta * s);
    }
#pragma unroll
    for (int j = 0; j < 8; ++j) dst[(size_t)tid * 8 + j] = tmp[j];
}

// ---------------- init GEMM (X @ W_init + b_init -> bf16 Xc0) ----------------
template<int K, int NTT, int NTW, int MT, bool SHARE, bool ADYN, bool ACCUM, bool BIAS, bool OUTBF>
__global__ __launch_bounds__(256) void gemm_mfma(
    const void* __restrict__ Av, const s8v* __restrict__ Bp,
    const void* __restrict__ bias,
    float* __restrict__ Cf, unsigned short* __restrict__ Cb,
    const int* __restrict__ flagp)
{
    const int f32 = (ADYN || BIAS) ? *flagp : 0;
    const int N    = NTT * 16;
    const int lane = threadIdx.x & 63;
    const int wid  = threadIdx.x >> 6;
    int mbase, nt0;
    if (SHARE) {
        mbase = blockIdx.x * (MT * 16);
        nt0   = wid * NTW;
    } else {
        const int job = blockIdx.x * 4 + wid;
        mbase = job * (MT * 16);
        nt0   = 0;
    }
    if (mbase >= NNODES) return;
    const int l15  = lane & 15;
    const int quad = lane >> 4;

    f4v acc[MT][NTW];
#pragma unroll
    for (int mt = 0; mt < MT; ++mt)
#pragma unroll
        for (int nt = 0; nt < NTW; ++nt)
            acc[mt][nt] = (f4v){0.f, 0.f, 0.f, 0.f};

#pragma unroll 4
    for (int ks = 0; ks < K / 32; ++ks) {
        const int kb = ks * 32 + quad * 8;
        s8v a[MT];
        if (ADYN && f32) {
            const float* Af = (const float*)Av;
#pragma unroll
            for (int mt = 0; mt < MT; ++mt) {
                const float4* p = (const float4*)(Af + (size_t)(mbase + mt * 16 + l15) * K + kb);
                float4 x0 = p[0], x1 = p[1];
                a[mt][0] = (short)f2bf(x0.x); a[mt][1] = (short)f2bf(x0.y);
                a[mt][2] = (short)f2bf(x0.z); a[mt][3] = (short)f2bf(x0.w);
                a[mt][4] = (short)f2bf(x1.x); a[mt][5] = (short)f2bf(x1.y);
                a[mt][6] = (short)f2bf(x1.z); a[mt][7] = (short)f2bf(x1.w);
            }
        } else {
            const unsigned short* A = (const unsigned short*)Av;
#pragma unroll
            for (int mt = 0; mt < MT; ++mt)
                a[mt] = *(const s8v*)(A + (size_t)(mbase + mt * 16 + l15) * K + kb);
        }
#pragma unroll
        for (int nt = 0; nt < NTW; ++nt) {
            s8v b = Bp[(ks * NTT + nt0 + nt) * 64 + lane];
#pragma unroll
            for (int mt = 0; mt < MT; ++mt)
                acc[mt][nt] = __builtin_amdgcn_mfma_f32_16x16x32_bf16(a[mt], b, acc[mt][nt], 0, 0, 0);
        }
    }

#pragma unroll
    for (int mt = 0; mt < MT; ++mt) {
#pragma unroll
        for (int nt = 0; nt < NTW; ++nt) {
#pragma unroll
            for (int r = 0; r < 4; ++r) {
                int row = mbase + mt * 16 + quad * 4 + r;
                int col = (nt0 + nt) * 16 + l15;
                float v = acc[mt][nt][r];
                if (BIAS) v += ldf(bias, col, f32);
                size_t idx = (size_t)row * N + col;
                if (OUTBF) {
                    Cb[idx] = f2bf(v);
                } else {
                    if (ACCUM) v += Cf[idx];
                    Cf[idx] = v;
                }
            }
        }
    }
}

// ---------------- fused SpMM + Xnext + (AX @ Wcomb -> Zacc) ----------------
// block = 16 nodes; wave s-loops 4 nodes. Split-wave gather: lanes 0-31 take even
// edges, 32-63 odd edges; each lane owns 8 feats (one 16B ushort8 load) -> one load
// instruction fetches TWO full rows (1KB). em read is nontemporal (pure streaming,
// keeps L2 for the gathered Xc rows). Halves merged per node via shfl_xor(32).
template<bool FIRST, bool LAST>
__global__ __launch_bounds__(256) void spmm_fused(
    const int* __restrict__ row_ptr, const long long* __restrict__ em,
    const unsigned short* __restrict__ Xc, unsigned short* __restrict__ Xn,
    const s8v* __restrict__ WcombL, const s8v* __restrict__ WsortP,
    const void* __restrict__ bsort, float* __restrict__ Zacc,
    const void* __restrict__ gammas, int layer, const int* __restrict__ flagp)
{
    __shared__ unsigned short axl[16 * 256];                    // 8KB, swizzled
    __shared__ unsigned short hxl[FIRST ? 16 * 256 : 4];        // 8KB when FIRST
    const int wid  = threadIdx.x >> 6;
    const int lane = threadIdx.x & 63;
    const int half = lane >> 5;          // 0: even edges, 1: odd edges
    const int l32  = lane & 31;          // feat group: feats l32*8 .. +7
    const int mbase = blockIdx.x * 16;
    const int f32 = *flagp;
    const float g = LAST ? 0.f : ldf(gammas, layer, f32);

    for (int s = 0; s < 4; ++s) {
        const int row  = wid * 4 + s;
        const int node = mbase + row;
        const int start = row_ptr[node];
        const int end   = row_ptr[node + 1];
        f2v acc[4];
#pragma unroll
        for (int k = 0; k < 4; ++k) acc[k] = (f2v){0.f, 0.f};

        int e = start;
        // deep-pipelined: 8 pairs = 16 edges, 8 independent 1KB gathers in flight
        for (; e + 16 <= end; e += 16) {
            long long m[8];
#pragma unroll
            for (int j = 0; j < 8; ++j) m[j] = __builtin_nontemporal_load(&em[e + 2 * j + half]);
            u8v q[8];
#pragma unroll
            for (int j = 0; j < 8; ++j)
                q[j] = *(const u8v*)(Xc + (size_t)em_col(m[j]) * NHID + l32 * 8);
#pragma unroll
            for (int j = 0; j < 8; ++j) {
                float w = em_w(m[j]);
                f2v wv = (f2v){w, w};
                u4v qw = __builtin_bit_cast(u4v, q[j]);
#pragma unroll
                for (int k = 0; k < 4; ++k) acc[k] += wv * ex2(qw[k]);
            }
        }
        for (; e + 2 <= end; e += 2) {
            long long m = __builtin_nontemporal_load(&em[e + half]);
            float w = em_w(m);
            f2v wv = (f2v){w, w};
            u8v q = *(const u8v*)(Xc + (size_t)em_col(m) * NHID + l32 * 8);
            u4v qw = __builtin_bit_cast(u4v, q);
#pragma unroll
            for (int k = 0; k < 4; ++k) acc[k] += wv * ex2(qw[k]);
        }
        if (e < end) {                     // odd leftover: half0 only (half1 adds 0)
            long long m = __builtin_nontemporal_load(&em[e]);
            float w = half ? 0.f : em_w(m);
            f2v wv = (f2v){w, w};
            u8v q = *(const u8v*)(Xc + (size_t)em_col(m) * NHID + l32 * 8);
            u4v qw = __builtin_bit_cast(u4v, q);
#pragma unroll
            for (int k = 0; k < 4; ++k) acc[k] += wv * ex2(qw[k]);
        }

        // merge even/odd halves: lane l and l+32 hold partial sums of same feats
        float a[8];
#pragma unroll
        for (int k = 0; k < 4; ++k) { a[2 * k] = acc[k].x; a[2 * k + 1] = acc[k].y; }
#pragma unroll
        for (int i = 0; i < 8; ++i) a[i] += __shfl_xor(a[i], 32, 64);

        const int loff = SW(row * 512 + l32 * 16, row);
        if (half == 0) {
            u8v ov;
#pragma unroll
            for (int i = 0; i < 8; ++i) ov[i] = f2bf(a[i]);
            *(u8v*)((char*)axl + loff) = ov;
        } else if (FIRST || !LAST) {
            u8v xi = *(const u8v*)(Xc + (size_t)node * NHID + l32 * 8);
            if constexpr (FIRST)
                *(u8v*)((char*)hxl + loff) = xi;
            if constexpr (!LAST) {
                u8v xn;
#pragma unroll
                for (int i = 0; i < 8; ++i) xn[i] = f2bf(g * (bf2f(xi[i]) - a[i]));
                *(u8v*)(Xn + (size_t)node * NHID + l32 * 8) = xn;
            }
        }
    }
    __syncthreads();

    // GEMM phase: wave owns n-tile wid (cols wid*16..+15)
    const int l15  = lane & 15;
    const int quad = lane >> 4;
    f4v gacc = (f4v){0.f, 0.f, 0.f, 0.f};
#pragma unroll
    for (int ks = 0; ks < NHID / 32; ++ks) {
        const int boff = SW(l15 * 512 + ks * 64 + quad * 16, l15);
        s8v av = *(const s8v*)((const char*)axl + boff);
        s8v b = WcombL[(ks * 4 + wid) * 64 + lane];
        gacc = __builtin_amdgcn_mfma_f32_16x16x32_bf16(av, b, gacc, 0, 0, 0);
        if constexpr (FIRST) {
            s8v h  = *(const s8v*)((const char*)hxl + boff);
            s8v b2 = WsortP[(ks * 4 + wid) * 64 + lane];
            gacc = __builtin_amdgcn_mfma_f32_16x16x32_bf16(h, b2, gacc, 0, 0, 0);
        }
    }
#pragma unroll
    for (int r = 0; r < 4; ++r) {
        const int orow = mbase + quad * 4 + r;
        const int col = wid * 16 + l15;
        const size_t idx = (size_t)orow * NCLS + col;
        float v = gacc[r];
        if constexpr (FIRST) Zacc[idx] = v + ldf(bsort, col, f32);
        else                 Zacc[idx] += v;
    }
}

// ---------------- log_softmax over 64 classes, one wave per row ----------------
__global__ __launch_bounds__(256) void lsm_kernel(const float* __restrict__ Z,
                                                  void* __restrict__ out,
                                                  const int* __restrict__ flagp) {
    const int f32 = *flagp;
    const int wid  = threadIdx.x >> 6;
    const int lane = threadIdx.x & 63;
    const int row  = blockIdx.x * 4 + wid;
    if (row >= NNODES) return;
    float z = Z[(size_t)row * NCLS + lane];
    float m = z;
#pragma unroll
    for (int off = 32; off >= 1; off >>= 1) m = fmaxf(m, __shfl_xor(m, off, 64));
    float s = __expf(z - m);
#pragma unroll
    for (int off = 32; off >= 1; off >>= 1) s += __shfl_xor(s, off, 64);
    float r = z - m - __logf(s);
    size_t idx = (size_t)row * NCLS + lane;
    if (f32) ((float*)out)[idx] = r;
    else     ((unsigned short*)out)[idx] = f2bf(r);
}

extern "C" void kernel_launch(void* const* d_in, const int* in_sizes, int n_in,
                              void* d_out, int out_size, void* d_ws, size_t ws_size,
                              hipStream_t stream)
{
    const void* X      = d_in[0];
    const int*  erow   = (const int*)d_in[1];
    const int*  ecol   = (const int*)d_in[2];
    const void* ew     = d_in[3];
    const void* Winit  = d_in[4];
    const void* binit  = d_in[5];
    const void* gammas = d_in[6];
    const void* Ws     = d_in[7];
    const void* Wsort  = d_in[8];
    const void* bsort  = d_in[9];

    char* p = (char*)d_ws;
    auto alloc = [&](size_t bytes) -> char* {
        char* r = p; p += (bytes + 255) & ~(size_t)255; return r;
    };
    int*            flag   = (int*)           alloc(256);
    float*          Zacc   = (float*)         alloc((size_t)NNODES * NCLS * 4);   // 25.6 MB
    unsigned short* Xc0    = (unsigned short*)alloc((size_t)NNODES * NHID * 2);   // 51.2 MB
    unsigned short* Xc1    = (unsigned short*)alloc((size_t)NNODES * NHID * 2);   // 51.2 MB
    int*            counts = (int*)           alloc((size_t)(NNODES + 1) * 4);
    int*            row_ptr= (int*)           alloc((size_t)(NNODES + 1) * 4);
    int*            cursor = (int*)           alloc((size_t)(NNODES + 1) * 4);
    int*            bsum   = (int*)           alloc((size_t)(SCAN_NB + 1) * 4);
    long long*      em     = (long long*)     alloc((size_t)NEDGES * 8);          // 25.6 MB
    unsigned short* WinitP = (unsigned short*)alloc((size_t)NFEAT * NHID * 2);
    unsigned short* WsortP = (unsigned short*)alloc((size_t)NHID * NCLS * 2);
    unsigned short* WcombP = (unsigned short*)alloc((size_t)NLAYERS * NHID * NCLS * 2);

    // dtype probe first — everything downstream branches on *flag
    probe_kernel<<<1, 64, 0, stream>>>((const unsigned short*)ew, flag);

    // CSR build (rebuilt every call)
    hipMemsetAsync(counts, 0, (size_t)NNODES * 4, stream);
    hist_kernel<<<NEDGES / 256, 256, 0, stream>>>(erow, counts);
    scan_local<<<SCAN_NB, 1024, 0, stream>>>(counts, row_ptr, bsum);
    scan_bsum<<<1, 64, 0, stream>>>(bsum);
    scan_add<<<SCAN_NB, 1024, 0, stream>>>(row_ptr, cursor, bsum);
    for (int pass = 0; pass < SC_NPASS; ++pass)
        scatter_pass<<<NEDGES / 256, 256, 0, stream>>>(
            erow, ecol, ew, cursor, em, flag,
            pass * (NNODES / SC_NPASS), (pass + 1) * (NNODES / SC_NPASS));

    // weight repack / precompute
    pack_b<NFEAT, NHID><<<64, 256, 0, stream>>>(Winit, WinitP, flag);
    pack_b<NHID, NCLS><<<8, 256, 0, stream>>>(Wsort, WsortP, flag);
    pack_wcomb<<<64, 256, 0, stream>>>(Ws, Wsort, WcombP, flag);

    // Xc0 = bf16(X @ W_init + b_init)
    gemm_mfma<NFEAT, 16, 4, 2, true, true, false, true, true>
        <<<NNODES / 32, 256, 0, stream>>>(X, (const s8v*)WinitP, binit, nullptr, Xc0, flag);

    unsigned short* cur = Xc0;
    unsigned short* nxt = Xc1;
    const int fgrid = NNODES / 16;   // 6250 blocks, 16 nodes each
    for (int l = 0; l < NLAYERS; ++l) {
        const s8v* Wl = (const s8v*)WcombP + (size_t)l * 2048;
        if (l == 0)
            spmm_fused<true, false><<<fgrid, 256, 0, stream>>>(
                row_ptr, em, cur, nxt, Wl, (const s8v*)WsortP, bsort, Zacc, gammas, l, flag);
        else if (l < NLAYERS - 1)
            spmm_fused<false, false><<<fgrid, 256, 0, stream>>>(
                row_ptr, em, cur, nxt, Wl, (const s8v*)WsortP, bsort, Zacc, gammas, l, flag);
        else
            spmm_fused<false, true><<<fgrid, 256, 0, stream>>>(
                row_ptr, em, cur, nxt, Wl, (const s8v*)WsortP, bsort, Zacc, gammas, l, flag);
        unsigned short* t = cur; cur = nxt; nxt = t;
    }

    lsm_kernel<<<NNODES / 4, 256, 0, stream>>>(Zacc, d_out, flag);
}

// Round 5
// 2815.782 us; speedup vs baseline: 1.0182x; 1.0182x over previous
//
#include <hip/hip_runtime.h>

#define NNODES 100000
#define NEDGES 3200000
#define NFEAT  512
#define NHID   256
#define NCLS   64
#define NLAYERS 8
#define SCAN_NB ((NNODES + 1023) / 1024)   // 98 blocks
#define SC_EPB 2048                         // edges per scatter chunk
#define SC_CHUNKS ((NEDGES + SC_EPB - 1) / SC_EPB)   // 1563

typedef short s8v __attribute__((ext_vector_type(8)));          // 8 bf16 (16B) MFMA frag
typedef unsigned short u8v __attribute__((ext_vector_type(8))); // 8 bf16 raw (16B)
typedef unsigned int u4v __attribute__((ext_vector_type(4)));   // 4 u32 (16B)
typedef float f4v __attribute__((ext_vector_type(4)));          // 4 f32 MFMA C/D frag
typedef float f2v __attribute__((ext_vector_type(2)));          // packed f32 pair

__device__ __forceinline__ float bf2f(unsigned short u) {
    union { unsigned int i; float f; } v; v.i = ((unsigned int)u) << 16; return v.f;
}
__device__ __forceinline__ unsigned short f2bf(float f) {
    union { float f; unsigned int u; } v; v.f = f;
    unsigned int u = v.u;
    u += 0x7FFFu + ((u >> 16) & 1u);   // RNE
    return (unsigned short)(u >> 16);
}
__device__ __forceinline__ float ldf(const void* p, size_t i, int f32) {
    return f32 ? ((const float*)p)[i] : bf2f(((const unsigned short*)p)[i]);
}
// combined edge record: low 32 = col, high 32 = f32 weight bits
__device__ __forceinline__ int em_col(long long m) { return (int)(unsigned int)m; }
__device__ __forceinline__ float em_w(long long m) {
    union { int i; float f; } u; u.i = (int)((unsigned long long)m >> 32); return u.f;
}
// expand packed 2x bf16 word -> f32 pair {lo, hi}
__device__ __forceinline__ f2v ex2(unsigned int v) {
    union { unsigned int u; float f; } lo, hi;
    lo.u = v << 16; hi.u = v & 0xFFFF0000u;
    return (f2v){lo.f, hi.f};
}
// LDS XOR swizzle: spread 512B-stride rows across banks (bits 4-6)
#define SW(off, row) ((off) ^ (((row) & 7) << 4))

// ---------------- dtype probe ----------------
__global__ void probe_kernel(const unsigned short* __restrict__ ew, int* __restrict__ flag) {
    int i = threadIdx.x;                       // 64 threads
    unsigned short v = ew[2 * i];
    bool bad = (v & 0x8000u) || (v > 0x3D80u);
    unsigned long long m = __ballot(bad);
    if (i == 0) *flag = (m != 0ull) ? 1 : 0;   // 1 => float32 storage
}

// ---------------- CSR build ----------------
__global__ void hist_kernel(const int* __restrict__ row, int* __restrict__ counts) {
    int e = blockIdx.x * 256 + threadIdx.x;
    if (e < NEDGES) atomicAdd(&counts[__builtin_nontemporal_load(row + e)], 1);
}

__global__ void scan_local(const int* __restrict__ counts, int* __restrict__ row_ptr,
                           int* __restrict__ bsum) {
    __shared__ int lds[1024];
    const int tid = threadIdx.x;
    const int i = blockIdx.x * 1024 + tid;
    int v = (i < NNODES) ? counts[i] : 0;
    lds[tid] = v;
    __syncthreads();
    for (int off = 1; off < 1024; off <<= 1) {
        int t = (tid >= off) ? lds[tid - off] : 0;
        __syncthreads();
        lds[tid] += t;
        __syncthreads();
    }
    if (i < NNODES) row_ptr[i] = lds[tid] - v;      // block-local exclusive
    if (tid == 1023) bsum[blockIdx.x] = lds[1023];  // block total
}

__global__ void scan_bsum(int* __restrict__ bsum) {
    if (threadIdx.x == 0) {
        int acc = 0;
        for (int i = 0; i < SCAN_NB; ++i) { int v = bsum[i]; bsum[i] = acc; acc += v; }
        bsum[SCAN_NB] = acc;
    }
}

__global__ void scan_add(int* __restrict__ row_ptr, int* __restrict__ cursor,
                         const int* __restrict__ bsum) {
    const int i = blockIdx.x * 1024 + threadIdx.x;
    if (i < NNODES) {
        int v = row_ptr[i] + bsum[blockIdx.x];
        row_ptr[i] = v;
        cursor[i]  = v;
    }
    if (i == NNODES) row_ptr[NNODES] = bsum[SCAN_NB];
}

// XCD-classed scatter: rows partitioned into 8 classes (r/12500). Block with
// blockIdx&7==cls writes only class-cls rows -> with round-robin block->XCD
// dispatch, ALL writers of any em cache line sit on ONE XCD, whose ~3.2MB em
// window fits its 4MB L2 -> lines fill completely before eviction (fixes the
// 198MB write-out: round-4 showed per-XCD partial-dirty lines defeat binning).
// erow is scanned 8x (sequential nt reads, cheap).
__global__ __launch_bounds__(256) void scatter_classed(
    const int* __restrict__ row, const int* __restrict__ col,
    const void* __restrict__ w, int* __restrict__ cursor,
    long long* __restrict__ em, const int* __restrict__ flagp)
{
    const int f32  = *flagp;
    const int cls  = blockIdx.x & 7;             // XCD class
    const int base = (blockIdx.x >> 3) * SC_EPB;
    for (int i = threadIdx.x; i < SC_EPB; i += 256) {
        int e = base + i;
        if (e >= NEDGES) break;
        int r = __builtin_nontemporal_load(row + e);
        if (r / 12500 != cls) continue;
        int c = __builtin_nontemporal_load(col + e);
        float wv = f32 ? __builtin_nontemporal_load((const float*)w + e)
                       : bf2f(__builtin_nontemporal_load((const unsigned short*)w + e));
        union { float f; unsigned int u; } uw; uw.f = wv;
        long long rec = ((long long)uw.u << 32) | (unsigned int)c;
        int pos = atomicAdd(&cursor[r], 1);
        em[pos] = rec;
    }
}

// ---------------- B-matrix repack into MFMA fragment order ----------------
template<int K, int N>
__global__ void pack_b(const void* __restrict__ src, unsigned short* __restrict__ dst,
                       const int* __restrict__ flagp) {
    const int f32 = *flagp;
    const int NT = N / 16;
    const int total = (K / 32) * NT * 64;
    int tid = blockIdx.x * 256 + threadIdx.x;
    if (tid >= total) return;
    int lane = tid & 63, rest = tid >> 6;
    int nt = rest % NT, ks = rest / NT;
    int n  = nt * 16 + (lane & 15);
    int kb = ks * 32 + (lane >> 4) * 8;
    unsigned short tmp[8];
#pragma unroll
    for (int j = 0; j < 8; ++j) tmp[j] = f2bf(ldf(src, (size_t)(kb + j) * N + n, f32));
#pragma unroll
    for (int j = 0; j < 8; ++j) dst[(size_t)tid * 8 + j] = tmp[j];
}

// Wcomb_l = ((1-beta_l) I + beta_l W_l) @ W_sort  (256 x 64), packed B-frag layout, bf16.
__global__ void pack_wcomb(const void* __restrict__ Ws, const void* __restrict__ Wsort,
                           unsigned short* __restrict__ dst, const int* __restrict__ flagp) {
    const int f32 = *flagp;
    int tid = blockIdx.x * 256 + threadIdx.x;
    if (tid >= 16384) return;
    int lane = tid & 63;
    int rest = tid >> 6;
    int nt = rest & 3;
    int ks = (rest >> 2) & 7;
    int l  = rest >> 5;
    int n  = nt * 16 + (lane & 15);
    int kb = ks * 32 + (lane >> 4) * 8;
    float beta = 0.5f / (float)(l + 1);
    float ombeta = 1.0f - beta;
    const size_t wl = (size_t)l * NHID * NHID;
    unsigned short tmp[8];
#pragma unroll
    for (int j = 0; j < 8; ++j) {
        int k = kb + j;
        float s = 0.0f;
        for (int q = 0; q < NHID; ++q)
            s = fmaf(ldf(Ws, wl + (size_t)k * NHID + q, f32),
                     ldf(Wsort, (size_t)q * NCLS + n, f32), s);
        tmp[j] = f2bf(ombeta * ldf(Wsort, (size_t)k * NCLS + n, f32) + beta * s);
    }
#pragma unroll
    for (int j = 0; j < 8; ++j) dst[(size_t)tid * 8 + j] = tmp[j];
}

// ---------------- init GEMM (X @ W_init + b_init -> bf16 Xc0) ----------------
template<int K, int NTT, int NTW, int MT, bool SHARE, bool ADYN, bool ACCUM, bool BIAS, bool OUTBF>
__global__ __launch_bounds__(256) void gemm_mfma(
    const void* __restrict__ Av, const s8v* __restrict__ Bp,
    const void* __restrict__ bias,
    float* __restrict__ Cf, unsigned short* __restrict__ Cb,
    const int* __restrict__ flagp)
{
    const int f32 = (ADYN || BIAS) ? *flagp : 0;
    const int N    = NTT * 16;
    const int lane = threadIdx.x & 63;
    const int wid  = threadIdx.x >> 6;
    int mbase, nt0;
    if (SHARE) {
        mbase = blockIdx.x * (MT * 16);
        nt0   = wid * NTW;
    } else {
        const int job = blockIdx.x * 4 + wid;
        mbase = job * (MT * 16);
        nt0   = 0;
    }
    if (mbase >= NNODES) return;
    const int l15  = lane & 15;
    const int quad = lane >> 4;

    f4v acc[MT][NTW];
#pragma unroll
    for (int mt = 0; mt < MT; ++mt)
#pragma unroll
        for (int nt = 0; nt < NTW; ++nt)
            acc[mt][nt] = (f4v){0.f, 0.f, 0.f, 0.f};

#pragma unroll 4
    for (int ks = 0; ks < K / 32; ++ks) {
        const int kb = ks * 32 + quad * 8;
        s8v a[MT];
        if (ADYN && f32) {
            const float* Af = (const float*)Av;
#pragma unroll
            for (int mt = 0; mt < MT; ++mt) {
                const float4* p = (const float4*)(Af + (size_t)(mbase + mt * 16 + l15) * K + kb);
                float4 x0 = p[0], x1 = p[1];
                a[mt][0] = (short)f2bf(x0.x); a[mt][1] = (short)f2bf(x0.y);
                a[mt][2] = (short)f2bf(x0.z); a[mt][3] = (short)f2bf(x0.w);
                a[mt][4] = (short)f2bf(x1.x); a[mt][5] = (short)f2bf(x1.y);
                a[mt][6] = (short)f2bf(x1.z); a[mt][7] = (short)f2bf(x1.w);
            }
        } else {
            const unsigned short* A = (const unsigned short*)Av;
#pragma unroll
            for (int mt = 0; mt < MT; ++mt)
                a[mt] = *(const s8v*)(A + (size_t)(mbase + mt * 16 + l15) * K + kb);
        }
#pragma unroll
        for (int nt = 0; nt < NTW; ++nt) {
            s8v b = Bp[(ks * NTT + nt0 + nt) * 64 + lane];
#pragma unroll
            for (int mt = 0; mt < MT; ++mt)
                acc[mt][nt] = __builtin_amdgcn_mfma_f32_16x16x32_bf16(a[mt], b, acc[mt][nt], 0, 0, 0);
        }
    }

#pragma unroll
    for (int mt = 0; mt < MT; ++mt) {
#pragma unroll
        for (int nt = 0; nt < NTW; ++nt) {
#pragma unroll
            for (int r = 0; r < 4; ++r) {
                int row = mbase + mt * 16 + quad * 4 + r;
                int col = (nt0 + nt) * 16 + l15;
                float v = acc[mt][nt][r];
                if (BIAS) v += ldf(bias, col, f32);
                size_t idx = (size_t)row * N + col;
                if (OUTBF) {
                    Cb[idx] = f2bf(v);
                } else {
                    if (ACCUM) v += Cf[idx];
                    Cf[idx] = v;
                }
            }
        }
    }
}

// ---------------- fused SpMM + Xnext + (AX @ Wcomb -> Zacc) ----------------
// block = 16 nodes; wave s-loops 4 nodes. Split-wave gather: lanes 0-31 take even
// edges, 32-63 odd edges; each lane owns 8 feats (one 16B ushort8 load) -> one load
// instruction fetches TWO full rows (1KB). em read is nontemporal (pure streaming,
// keeps L2 for the gathered Xc rows). Halves merged per node via shfl_xor(32).
template<bool FIRST, bool LAST>
__global__ __launch_bounds__(256) void spmm_fused(
    const int* __restrict__ row_ptr, const long long* __restrict__ em,
    const unsigned short* __restrict__ Xc, unsigned short* __restrict__ Xn,
    const s8v* __restrict__ WcombL, const s8v* __restrict__ WsortP,
    const void* __restrict__ bsort, float* __restrict__ Zacc,
    const void* __restrict__ gammas, int layer, const int* __restrict__ flagp)
{
    __shared__ unsigned short axl[16 * 256];                    // 8KB, swizzled
    __shared__ unsigned short hxl[FIRST ? 16 * 256 : 4];        // 8KB when FIRST
    const int wid  = threadIdx.x >> 6;
    const int lane = threadIdx.x & 63;
    const int half = lane >> 5;          // 0: even edges, 1: odd edges
    const int l32  = lane & 31;          // feat group: feats l32*8 .. +7
    const int mbase = blockIdx.x * 16;
    const int f32 = *flagp;
    const float g = LAST ? 0.f : ldf(gammas, layer, f32);

    for (int s = 0; s < 4; ++s) {
        const int row  = wid * 4 + s;
        const int node = mbase + row;
        const int start = row_ptr[node];
        const int end   = row_ptr[node + 1];
        f2v acc[4];
#pragma unroll
        for (int k = 0; k < 4; ++k) acc[k] = (f2v){0.f, 0.f};

        int e = start;
        // deep-pipelined: 8 pairs = 16 edges, 8 independent 1KB gathers in flight
        for (; e + 16 <= end; e += 16) {
            long long m[8];
#pragma unroll
            for (int j = 0; j < 8; ++j) m[j] = __builtin_nontemporal_load(&em[e + 2 * j + half]);
            u8v q[8];
#pragma unroll
            for (int j = 0; j < 8; ++j)
                q[j] = *(const u8v*)(Xc + (size_t)em_col(m[j]) * NHID + l32 * 8);
#pragma unroll
            for (int j = 0; j < 8; ++j) {
                float w = em_w(m[j]);
                f2v wv = (f2v){w, w};
                u4v qw = __builtin_bit_cast(u4v, q[j]);
#pragma unroll
                for (int k = 0; k < 4; ++k) acc[k] += wv * ex2(qw[k]);
            }
        }
        for (; e + 2 <= end; e += 2) {
            long long m = __builtin_nontemporal_load(&em[e + half]);
            float w = em_w(m);
            f2v wv = (f2v){w, w};
            u8v q = *(const u8v*)(Xc + (size_t)em_col(m) * NHID + l32 * 8);
            u4v qw = __builtin_bit_cast(u4v, q);
#pragma unroll
            for (int k = 0; k < 4; ++k) acc[k] += wv * ex2(qw[k]);
        }
        if (e < end) {                     // odd leftover: half0 only (half1 adds 0)
            long long m = __builtin_nontemporal_load(&em[e]);
            float w = half ? 0.f : em_w(m);
            f2v wv = (f2v){w, w};
            u8v q = *(const u8v*)(Xc + (size_t)em_col(m) * NHID + l32 * 8);
            u4v qw = __builtin_bit_cast(u4v, q);
#pragma unroll
            for (int k = 0; k < 4; ++k) acc[k] += wv * ex2(qw[k]);
        }

        // merge even/odd halves: lane l and l+32 hold partial sums of same feats
        float a[8];
#pragma unroll
        for (int k = 0; k < 4; ++k) { a[2 * k] = acc[k].x; a[2 * k + 1] = acc[k].y; }
#pragma unroll
        for (int i = 0; i < 8; ++i) a[i] += __shfl_xor(a[i], 32, 64);

        const int loff = SW(row * 512 + l32 * 16, row);
        if (half == 0) {
            u8v ov;
#pragma unroll
            for (int i = 0; i < 8; ++i) ov[i] = f2bf(a[i]);
            *(u8v*)((char*)axl + loff) = ov;
        } else if (FIRST || !LAST) {
            u8v xi = *(const u8v*)(Xc + (size_t)node * NHID + l32 * 8);
            if constexpr (FIRST)
                *(u8v*)((char*)hxl + loff) = xi;
            if constexpr (!LAST) {
                u8v xn;
#pragma unroll
                for (int i = 0; i < 8; ++i) xn[i] = f2bf(g * (bf2f(xi[i]) - a[i]));
                *(u8v*)(Xn + (size_t)node * NHID + l32 * 8) = xn;
            }
        }
    }
    __syncthreads();

    // GEMM phase: wave owns n-tile wid (cols wid*16..+15)
    const int l15  = lane & 15;
    const int quad = lane >> 4;
    f4v gacc = (f4v){0.f, 0.f, 0.f, 0.f};
#pragma unroll
    for (int ks = 0; ks < NHID / 32; ++ks) {
        const int boff = SW(l15 * 512 + ks * 64 + quad * 16, l15);
        s8v av = *(const s8v*)((const char*)axl + boff);
        s8v b = WcombL[(ks * 4 + wid) * 64 + lane];
        gacc = __builtin_amdgcn_mfma_f32_16x16x32_bf16(av, b, gacc, 0, 0, 0);
        if constexpr (FIRST) {
            s8v h  = *(const s8v*)((const char*)hxl + boff);
            s8v b2 = WsortP[(ks * 4 + wid) * 64 + lane];
            gacc = __builtin_amdgcn_mfma_f32_16x16x32_bf16(h, b2, gacc, 0, 0, 0);
        }
    }
#pragma unroll
    for (int r = 0; r < 4; ++r) {
        const int orow = mbase + quad * 4 + r;
        const int col = wid * 16 + l15;
        const size_t idx = (size_t)orow * NCLS + col;
        float v = gacc[r];
        if constexpr (FIRST) Zacc[idx] = v + ldf(bsort, col, f32);
        else                 Zacc[idx] += v;
    }
}

// ---------------- log_softmax over 64 classes, one wave per row ----------------
__global__ __launch_bounds__(256) void lsm_kernel(const float* __restrict__ Z,
                                                  void* __restrict__ out,
                                                  const int* __restrict__ flagp) {
    const int f32 = *flagp;
    const int wid  = threadIdx.x >> 6;
    const int lane = threadIdx.x & 63;
    const int row  = blockIdx.x * 4 + wid;
    if (row >= NNODES) return;
    float z = Z[(size_t)row * NCLS + lane];
    float m = z;
#pragma unroll
    for (int off = 32; off >= 1; off >>= 1) m = fmaxf(m, __shfl_xor(m, off, 64));
    float s = __expf(z - m);
#pragma unroll
    for (int off = 32; off >= 1; off >>= 1) s += __shfl_xor(s, off, 64);
    float r = z - m - __logf(s);
    size_t idx = (size_t)row * NCLS + lane;
    if (f32) ((float*)out)[idx] = r;
    else     ((unsigned short*)out)[idx] = f2bf(r);
}

extern "C" void kernel_launch(void* const* d_in, const int* in_sizes, int n_in,
                              void* d_out, int out_size, void* d_ws, size_t ws_size,
                              hipStream_t stream)
{
    const void* X      = d_in[0];
    const int*  erow   = (const int*)d_in[1];
    const int*  ecol   = (const int*)d_in[2];
    const void* ew     = d_in[3];
    const void* Winit  = d_in[4];
    const void* binit  = d_in[5];
    const void* gammas = d_in[6];
    const void* Ws     = d_in[7];
    const void* Wsort  = d_in[8];
    const void* bsort  = d_in[9];

    char* p = (char*)d_ws;
    auto alloc = [&](size_t bytes) -> char* {
        char* r = p; p += (bytes + 255) & ~(size_t)255; return r;
    };
    int*            flag   = (int*)           alloc(256);
    float*          Zacc   = (float*)         alloc((size_t)NNODES * NCLS * 4);   // 25.6 MB
    unsigned short* Xc0    = (unsigned short*)alloc((size_t)NNODES * NHID * 2);   // 51.2 MB
    unsigned short* Xc1    = (unsigned short*)alloc((size_t)NNODES * NHID * 2);   // 51.2 MB
    int*            counts = (int*)           alloc((size_t)(NNODES + 1) * 4);
    int*            row_ptr= (int*)           alloc((size_t)(NNODES + 1) * 4);
    int*            cursor = (int*)           alloc((size_t)(NNODES + 1) * 4);
    int*            bsum   = (int*)           alloc((size_t)(SCAN_NB + 1) * 4);
    long long*      em     = (long long*)     alloc((size_t)NEDGES * 8);          // 25.6 MB
    unsigned short* WinitP = (unsigned short*)alloc((size_t)NFEAT * NHID * 2);
    unsigned short* WsortP = (unsigned short*)alloc((size_t)NHID * NCLS * 2);
    unsigned short* WcombP = (unsigned short*)alloc((size_t)NLAYERS * NHID * NCLS * 2);

    // dtype probe first — everything downstream branches on *flag
    probe_kernel<<<1, 64, 0, stream>>>((const unsigned short*)ew, flag);

    // CSR build (rebuilt every call)
    hipMemsetAsync(counts, 0, (size_t)NNODES * 4, stream);
    hist_kernel<<<NEDGES / 256, 256, 0, stream>>>(erow, counts);
    scan_local<<<SCAN_NB, 1024, 0, stream>>>(counts, row_ptr, bsum);
    scan_bsum<<<1, 64, 0, stream>>>(bsum);
    scan_add<<<SCAN_NB, 1024, 0, stream>>>(row_ptr, cursor, bsum);
    scatter_classed<<<SC_CHUNKS * 8, 256, 0, stream>>>(erow, ecol, ew, cursor, em, flag);

    // weight repack / precompute
    pack_b<NFEAT, NHID><<<64, 256, 0, stream>>>(Winit, WinitP, flag);
    pack_b<NHID, NCLS><<<8, 256, 0, stream>>>(Wsort, WsortP, flag);
    pack_wcomb<<<64, 256, 0, stream>>>(Ws, Wsort, WcombP, flag);

    // Xc0 = bf16(X @ W_init + b_init)
    gemm_mfma<NFEAT, 16, 4, 2, true, true, false, true, true>
        <<<NNODES / 32, 256, 0, stream>>>(X, (const s8v*)WinitP, binit, nullptr, Xc0, flag);

    unsigned short* cur = Xc0;
    unsigned short* nxt = Xc1;
    const int fgrid = NNODES / 16;   // 6250 blocks, 16 nodes each
    for (int l = 0; l < NLAYERS; ++l) {
        const s8v* Wl = (const s8v*)WcombP + (size_t)l * 2048;
        if (l == 0)
            spmm_fused<true, false><<<fgrid, 256, 0, stream>>>(
                row_ptr, em, cur, nxt, Wl, (const s8v*)WsortP, bsort, Zacc, gammas, l, flag);
        else if (l < NLAYERS - 1)
            spmm_fused<false, false><<<fgrid, 256, 0, stream>>>(
                row_ptr, em, cur, nxt, Wl, (const s8v*)WsortP, bsort, Zacc, gammas, l, flag);
        else
            spmm_fused<false, true><<<fgrid, 256, 0, stream>>>(
                row_ptr, em, cur, nxt, Wl, (const s8v*)WsortP, bsort, Zacc, gammas, l, flag);
        unsigned short* t = cur; cur = nxt; nxt = t;
    }

    lsm_kernel<<<NNODES / 4, 256, 0, stream>>>(Zacc, d_out, flag);
}